// Round 1
// baseline (769.089 us; speedup 1.0000x reference)
//
#include <hip/hip_runtime.h>
#include <math.h>

// Problem constants
#define BB 16
#define NN 1024
#define DD 512
#define KK 8
#define EPS_ 1e-8f
#define LN_EPS_ 1e-5f
// -0.5 * D * log(2*pi)
#define GLL_C0 (-470.4965290007924f)

// ---------------------------------------------------------------------------
// 1) Per-row LayerNorm stats: mean + rstd per (b,n) row. One wave per row.
// ---------------------------------------------------------------------------
__global__ __launch_bounds__(256) void ln_stats_kernel(
    const float* __restrict__ emb, float* __restrict__ rowstats)
{
    int row  = blockIdx.x * 4 + (threadIdx.x >> 6);
    int lane = threadIdx.x & 63;
    const float* e = emb + (size_t)row * DD;
    float v[8];
    float s = 0.0f;
#pragma unroll
    for (int j = 0; j < 8; j++) { v[j] = e[lane + 64 * j]; s += v[j]; }
#pragma unroll
    for (int off = 32; off; off >>= 1) s += __shfl_xor(s, off);
    float m = s * (1.0f / DD);
    float vs = 0.0f;
#pragma unroll
    for (int j = 0; j < 8; j++) { float d = v[j] - m; vs = fmaf(d, d, vs); }
#pragma unroll
    for (int off = 32; off; off >>= 1) vs += __shfl_xor(vs, off);
    float rstd = rsqrtf(vs * (1.0f / DD) + LN_EPS_);
    if (lane == 0) { rowstats[row * 2] = m; rowstats[row * 2 + 1] = rstd; }
}

// ---------------------------------------------------------------------------
// 2) Fused LN + GEMM: C = LN(emb) @ W + bias. 64x64 tile, 4x4 per thread.
//    grid.z selects (Wk,bk)->keys vs (Wv,bv)->values.
// ---------------------------------------------------------------------------
__global__ __launch_bounds__(256) void gemm_kernel(
    const float* __restrict__ emb, const float* __restrict__ rowstats,
    const float* __restrict__ lng, const float* __restrict__ lnb,
    const float* __restrict__ Wk, const float* __restrict__ bk,
    const float* __restrict__ Wv, const float* __restrict__ bv,
    float* __restrict__ keys, float* __restrict__ values)
{
    const float* W;
    const float* bias;
    float* C;
    if (blockIdx.z == 0) { W = Wk; bias = bk; C = keys; }
    else                 { W = Wv; bias = bv; C = values; }

    int row0 = blockIdx.y * 64;
    int col0 = blockIdx.x * 64;
    int tid  = threadIdx.x;
    int tx = tid & 15, ty = tid >> 4;

    __shared__ float As[16][64];
    __shared__ float Bs[16][64];

    // A staging thread mapping: r = tid>>2 (row in tile), kq = (tid&3)*4
    int ar = tid >> 2;
    int kq = (tid & 3) * 4;
    size_t arow = (size_t)(row0 + ar);
    float  am   = rowstats[arow * 2];
    float  arstd = rowstats[arow * 2 + 1];
    // B staging: kk = tid>>4, c4 = (tid&15)*4
    int bkk = tid >> 4;
    int bc4 = (tid & 15) * 4;

    float acc[4][4] = {};

    for (int k0 = 0; k0 < DD; k0 += 16) {
        float4 ev = *(const float4*)&emb[arow * DD + k0 + kq];
        float4 gv = *(const float4*)&lng[k0 + kq];
        float4 bv2 = *(const float4*)&lnb[k0 + kq];
        float4 wv = *(const float4*)&W[(size_t)(k0 + bkk) * DD + col0 + bc4];

        __syncthreads();
        As[kq + 0][ar] = fmaf((ev.x - am) * arstd, gv.x, bv2.x);
        As[kq + 1][ar] = fmaf((ev.y - am) * arstd, gv.y, bv2.y);
        As[kq + 2][ar] = fmaf((ev.z - am) * arstd, gv.z, bv2.z);
        As[kq + 3][ar] = fmaf((ev.w - am) * arstd, gv.w, bv2.w);
        *(float4*)&Bs[bkk][bc4] = wv;
        __syncthreads();

#pragma unroll
        for (int kk = 0; kk < 16; kk++) {
            float a[4], b[4];
            *(float4*)a = *(const float4*)&As[kk][ty * 4];
            *(float4*)b = *(const float4*)&Bs[kk][tx * 4];
#pragma unroll
            for (int i = 0; i < 4; i++)
#pragma unroll
                for (int j = 0; j < 4; j++)
                    acc[i][j] = fmaf(a[i], b[j], acc[i][j]);
        }
    }

    float4 bb = *(const float4*)&bias[col0 + tx * 4];
#pragma unroll
    for (int i = 0; i < 4; i++) {
        int row = row0 + ty * 4 + i;
        float4 o;
        o.x = acc[i][0] + bb.x;
        o.y = acc[i][1] + bb.y;
        o.z = acc[i][2] + bb.z;
        o.w = acc[i][3] + bb.w;
        *(float4*)&C[(size_t)row * DD + col0 + tx * 4] = o;
    }
}

// ---------------------------------------------------------------------------
// 3) Init: slots = mu0 + exp(logsigma)*noise_init; queries = slots@Wq + bq;
//    sigma = exp(logsigma); mixing = mixing_coeffs. One block per (b,k).
// ---------------------------------------------------------------------------
__global__ __launch_bounds__(256) void init_kernel(
    const float* __restrict__ noise_init, const float* __restrict__ slots_mu,
    const float* __restrict__ slots_logsigma, const float* __restrict__ mixing_coeffs,
    const float* __restrict__ Wq, const float* __restrict__ bq,
    float* __restrict__ queries, float* __restrict__ sigma, float* __restrict__ mixing)
{
    int b = blockIdx.x >> 3;
    int k = blockIdx.x & 7;
    int tid = threadIdx.x;
    __shared__ float s[DD];
    for (int d = tid; d < DD; d += 256) {
        float sg = expf(slots_logsigma[k * DD + d]);
        s[d] = fmaf(sg, noise_init[((size_t)(b * KK + k)) * DD + d], slots_mu[k * DD + d]);
        sigma[((size_t)(b * KK + k)) * DD + d] = sg;
    }
    __syncthreads();
    for (int col = tid; col < DD; col += 256) {
        float q = bq[col];
        for (int d = 0; d < DD; d++) q = fmaf(s[d], Wq[(size_t)d * DD + col], q);
        queries[((size_t)(b * KK + k)) * DD + col] = q;
    }
    if (tid == 0) mixing[b * KK + k] = mixing_coeffs[k];
}

// ---------------------------------------------------------------------------
// 4) Prep (per iteration): invvar = 1/(sigma^2+eps), logdet = sum log(|sigma|+eps)
// ---------------------------------------------------------------------------
__global__ __launch_bounds__(256) void prep_kernel(
    const float* __restrict__ sigma, float* __restrict__ invvar, float* __restrict__ logdet)
{
    int bk = blockIdx.x;
    int tid = threadIdx.x;
    float lsum = 0.0f;
    for (int d = tid; d < DD; d += 256) {
        float sg = sigma[(size_t)bk * DD + d];
        invvar[(size_t)bk * DD + d] = 1.0f / (sg * sg + EPS_);
        lsum += logf(fabsf(sg) + EPS_);
    }
    __shared__ float red[256];
    red[tid] = lsum;
    __syncthreads();
    for (int s2 = 128; s2 > 0; s2 >>= 1) {
        if (tid < s2) red[tid] += red[tid + s2];
        __syncthreads();
    }
    if (tid == 0) logdet[bk] = red[0];
}

// ---------------------------------------------------------------------------
// 5) gll + K-normalized attn + colsum accumulation. One wave per n-row.
// ---------------------------------------------------------------------------
#define GLL_ROWS 16
__global__ __launch_bounds__(256) void gll_kernel(
    const float* __restrict__ keys, const float* __restrict__ queries,
    const float* __restrict__ invvar, const float* __restrict__ logdet,
    const float* __restrict__ mixing, float* __restrict__ attn, float* __restrict__ colsum)
{
    int b  = blockIdx.y;
    int n0 = blockIdx.x * GLL_ROWS;
    int tid = threadIdx.x;

    __shared__ float qs[KK * DD];
    __shared__ float ivs[KK * DD];
    __shared__ float s_ld[KK];
    __shared__ float s_mix[KK];

    const float* qg = queries + (size_t)b * KK * DD;
    const float* ig = invvar + (size_t)b * KK * DD;
    for (int i = tid; i < KK * DD / 4; i += 256) {
        ((float4*)qs)[i]  = ((const float4*)qg)[i];
        ((float4*)ivs)[i] = ((const float4*)ig)[i];
    }
    if (tid < KK) {
        s_ld[tid]  = logdet[b * KK + tid];
        s_mix[tid] = mixing[b * KK + tid];
    }
    __syncthreads();

    int wave = tid >> 6, lane = tid & 63;
    float cs_acc = 0.0f;

    for (int i = 0; i < GLL_ROWS / 4; i++) {
        int n = n0 + wave * (GLL_ROWS / 4) + i;
        const float* krow = keys + ((size_t)(b * NN + n)) * DD;
        float kv[8];
#pragma unroll
        for (int j = 0; j < 8; j++) kv[j] = krow[lane + 64 * j];

        float p[KK];
#pragma unroll
        for (int k = 0; k < KK; k++) {
            float s = 0.0f;
#pragma unroll
            for (int j = 0; j < 8; j++) {
                int d = lane + 64 * j;
                float df = kv[j] - qs[k * DD + d];
                s = fmaf(df * df, ivs[k * DD + d], s);
            }
            p[k] = s;
        }
#pragma unroll
        for (int off = 32; off; off >>= 1) {
#pragma unroll
            for (int k = 0; k < KK; k++) p[k] += __shfl_xor(p[k], off);
        }
        // all lanes now have all K sums
        float a[KK];
        float den = 0.0f;
#pragma unroll
        for (int k = 0; k < KK; k++) {
            float g = GLL_C0 - 0.5f * s_ld[k] - 0.5f * p[k];
            a[k] = s_mix[k] * g;
            den += a[k];
        }
        float rden = 1.0f / den;
        if (lane < KK) {
            float v = 0.0f;
#pragma unroll
            for (int k = 0; k < KK; k++)
                if (lane == k) v = a[k] * rden;
            attn[((size_t)(b * NN + n)) * KK + lane] = v;
            cs_acc += v;
        }
    }
    if (lane < KK) atomicAdd(&colsum[b * KK + lane], cs_acc);
}

// ---------------------------------------------------------------------------
// 6) mu/sigma one-pass update + mixing update.
//    sigma = Sv2 - mu^2*(2 - s), s = colsum/(colsum+eps)
// ---------------------------------------------------------------------------
__global__ __launch_bounds__(128) void musigma_kernel(
    const float* __restrict__ values, const float* __restrict__ attn,
    const float* __restrict__ colsum, float* __restrict__ mu,
    float* __restrict__ sigma, float* __restrict__ mixing)
{
    int b = blockIdx.y;
    int d = blockIdx.x * 128 + threadIdx.x;
    __shared__ float asml[64 * KK];
    float s1[KK] = {};
    float s2[KK] = {};
    const float* ab = attn + (size_t)b * NN * KK;

    for (int nc = 0; nc < NN; nc += 64) {
        __syncthreads();
        ((float4*)asml)[threadIdx.x] = ((const float4*)(ab + nc * KK))[threadIdx.x];
        __syncthreads();
#pragma unroll 4
        for (int nn = 0; nn < 64; nn++) {
            float v = values[((size_t)(b * NN + nc + nn)) * DD + d];
#pragma unroll
            for (int k = 0; k < KK; k++) {
                float a = asml[nn * KK + k];
                s1[k] = fmaf(a, v, s1[k]);
                s2[k] = fmaf(a * v, v, s2[k]);
            }
        }
    }
#pragma unroll
    for (int k = 0; k < KK; k++) {
        float cs  = colsum[b * KK + k];
        float inv = 1.0f / (cs + EPS_);
        float m   = s1[k] * inv;
        float sv2 = s2[k] * inv;
        float ssum = cs * inv;
        mu[((size_t)(b * KK + k)) * DD + d] = m;
        sigma[((size_t)(b * KK + k)) * DD + d] = sv2 - m * m * (2.0f - ssum);
    }
    if (blockIdx.x == 0 && threadIdx.x < KK) {
        int k = threadIdx.x;
        float cs = colsum[b * KK + k];
        mixing[b * KK + k] = (cs / (cs + EPS_)) * (1.0f / NN);
    }
}

// ---------------------------------------------------------------------------
// 7) Final outputs: slots = mu + max(|sigma|,eps)*noise_final ; attn^T
// ---------------------------------------------------------------------------
__global__ __launch_bounds__(256) void final_kernel(
    const float* __restrict__ mu, const float* __restrict__ sigma,
    const float* __restrict__ noise_final, const float* __restrict__ attn,
    const float* __restrict__ colsum, float* __restrict__ out)
{
    int gid = blockIdx.x * 256 + threadIdx.x;
    if (gid < BB * KK * DD) {
        float s = fmaxf(fabsf(sigma[gid]), EPS_);
        out[gid] = fmaf(s, noise_final[gid], mu[gid]);
    }
    if (gid < BB * KK * NN) {
        int b = gid >> 13;
        int k = (gid >> 10) & 7;
        int n = gid & 1023;
        float cs = colsum[b * KK + k];
        out[BB * KK * DD + gid] = attn[((size_t)(b * NN + n)) * KK + k] / (cs + EPS_);
    }
}

// ---------------------------------------------------------------------------
extern "C" void kernel_launch(void* const* d_in, const int* in_sizes, int n_in,
                              void* d_out, int out_size, void* d_ws, size_t ws_size,
                              hipStream_t stream)
{
    const float* emb         = (const float*)d_in[0];
    const float* noise_init  = (const float*)d_in[1];
    const float* noise_final = (const float*)d_in[2];
    const float* slots_mu    = (const float*)d_in[3];
    const float* slots_logsg = (const float*)d_in[4];
    const float* mixing_co   = (const float*)d_in[5];
    const float* Wk          = (const float*)d_in[6];
    const float* bk          = (const float*)d_in[7];
    const float* Wq          = (const float*)d_in[8];
    const float* bq          = (const float*)d_in[9];
    const float* Wv          = (const float*)d_in[10];
    const float* bv          = (const float*)d_in[11];
    const float* ln_g        = (const float*)d_in[12];
    const float* ln_b        = (const float*)d_in[13];
    float* out = (float*)d_out;

    // workspace layout (floats)
    float* ws = (float*)d_ws;
    float* keys     = ws;                         // 16384*512
    float* values   = keys + (size_t)BB * NN * DD;   // 16384*512
    float* queries  = values + (size_t)BB * NN * DD; // 65536
    float* sigma    = queries + BB * KK * DD;        // 65536
    float* invvar   = sigma + BB * KK * DD;          // 65536
    float* mu       = invvar + BB * KK * DD;         // 65536
    float* attn     = mu + BB * KK * DD;             // 131072
    float* rowstats = attn + BB * NN * KK;           // 32768
    float* logdet   = rowstats + 2 * BB * NN;        // 128
    float* mixing   = logdet + BB * KK;              // 128
    float* colsum   = mixing + BB * KK;              // 128

    ln_stats_kernel<<<BB * NN / 4, 256, 0, stream>>>(emb, rowstats);

    gemm_kernel<<<dim3(DD / 64, BB * NN / 64, 2), 256, 0, stream>>>(
        emb, rowstats, ln_g, ln_b, Wk, bk, Wv, bv, keys, values);

    init_kernel<<<BB * KK, 256, 0, stream>>>(
        noise_init, slots_mu, slots_logsg, mixing_co, Wq, bq, queries, sigma, mixing);

    for (int it = 0; it < 3; it++) {
        prep_kernel<<<BB * KK, 256, 0, stream>>>(sigma, invvar, logdet);
        hipMemsetAsync(colsum, 0, BB * KK * sizeof(float), stream);
        gll_kernel<<<dim3(NN / GLL_ROWS, BB), 256, 0, stream>>>(
            keys, queries, invvar, logdet, mixing, attn, colsum);
        musigma_kernel<<<dim3(DD / 128, BB), 128, 0, stream>>>(
            values, attn, colsum, mu, sigma, mixing);
    }

    final_kernel<<<(BB * KK * NN + 255) / 256, 256, 0, stream>>>(
        mu, sigma, noise_final, attn, colsum, out);
}

// Round 2
// 313.337 us; speedup vs baseline: 2.4545x; 2.4545x over previous
//
#include <hip/hip_runtime.h>
#include <math.h>

// Problem constants
#define BB 16
#define NN 1024
#define DD 512
#define KK 8
#define EPS_ 1e-8f
#define LN_EPS_ 1e-5f
// -0.5 * D * log(2*pi)
#define GLL_C0 (-470.4965290007924f)

typedef __attribute__((ext_vector_type(8))) short short8;
typedef __attribute__((ext_vector_type(4))) float f32x4;

// round-to-nearest-even f32 -> bf16 (as short)
static __device__ inline short f2bf(float f) {
    unsigned u = __builtin_bit_cast(unsigned, f);
    u = (u + 0x7fff + ((u >> 16) & 1)) >> 16;
    return (short)u;
}

static __device__ inline void gload16(const void* g, void* l) {
    __builtin_amdgcn_global_load_lds(
        (const __attribute__((address_space(1))) void*)g,
        (__attribute__((address_space(3))) void*)l, 16, 0, 0);
}

// ---------------------------------------------------------------------------
// 1) Fused LayerNorm + cast to bf16: Abf[row][d] = LN(emb)[row][d] in bf16.
//    One wave per row; lane owns 8 consecutive d (32B coalesced loads,
//    16B bf16x8 stores).
// ---------------------------------------------------------------------------
__global__ __launch_bounds__(256) void ln_bf_kernel(
    const float* __restrict__ emb, const float* __restrict__ lng,
    const float* __restrict__ lnb, short* __restrict__ Abf)
{
    int row  = blockIdx.x * 4 + (threadIdx.x >> 6);
    int lane = threadIdx.x & 63;
    const float* e = emb + (size_t)row * DD + lane * 8;
    float4 v0 = *(const float4*)e;
    float4 v1 = *(const float4*)(e + 4);
    float v[8] = {v0.x, v0.y, v0.z, v0.w, v1.x, v1.y, v1.z, v1.w};
    float s = 0.0f;
#pragma unroll
    for (int j = 0; j < 8; j++) s += v[j];
#pragma unroll
    for (int off = 32; off; off >>= 1) s += __shfl_xor(s, off);
    float m = s * (1.0f / DD);
    float vs = 0.0f;
#pragma unroll
    for (int j = 0; j < 8; j++) { float d = v[j] - m; vs = fmaf(d, d, vs); }
#pragma unroll
    for (int off = 32; off; off >>= 1) vs += __shfl_xor(vs, off);
    float rstd = rsqrtf(vs * (1.0f / DD) + LN_EPS_);

    float4 g0 = *(const float4*)&lng[lane * 8];
    float4 g1 = *(const float4*)&lng[lane * 8 + 4];
    float4 b0 = *(const float4*)&lnb[lane * 8];
    float4 b1 = *(const float4*)&lnb[lane * 8 + 4];
    float g[8] = {g0.x, g0.y, g0.z, g0.w, g1.x, g1.y, g1.z, g1.w};
    float bb[8] = {b0.x, b0.y, b0.z, b0.w, b1.x, b1.y, b1.z, b1.w};
    short8 o;
#pragma unroll
    for (int j = 0; j < 8; j++) o[j] = f2bf(fmaf((v[j] - m) * rstd, g[j], bb[j]));
    *(short8*)&Abf[(size_t)row * DD + lane * 8] = o;
}

// ---------------------------------------------------------------------------
// 2) Transpose + cast weights: Wt[z][n][k] = bf16(W_z[k][n]).  z: 0=Wk,1=Wv,2=Wq
// ---------------------------------------------------------------------------
__global__ __launch_bounds__(256) void wtrans_kernel(
    const float* __restrict__ Wk, const float* __restrict__ Wv,
    const float* __restrict__ Wq, short* __restrict__ Wt)
{
    const float* W = (blockIdx.z == 0) ? Wk : (blockIdx.z == 1) ? Wv : Wq;
    short* T = Wt + (size_t)blockIdx.z * DD * DD;
    int k0 = blockIdx.x * 32, n0 = blockIdx.y * 32;
    int tx = threadIdx.x & 31, ty = threadIdx.x >> 5;
    __shared__ float t[32][33];
#pragma unroll
    for (int p = 0; p < 4; p++)
        t[ty + p * 8][tx] = W[(size_t)(k0 + ty + p * 8) * DD + n0 + tx];
    __syncthreads();
#pragma unroll
    for (int p = 0; p < 4; p++)
        T[(size_t)(n0 + ty + p * 8) * DD + k0 + tx] = f2bf(t[tx][ty + p * 8]);
}

// ---------------------------------------------------------------------------
// 3) Init: slots (bf16) = mu0 + exp(logsigma)*noise_init; sigma = exp(logsigma);
//    mixing = mixing_coeffs. One block per (b,k).
// ---------------------------------------------------------------------------
__global__ __launch_bounds__(256) void init_small_kernel(
    const float* __restrict__ noise_init, const float* __restrict__ slots_mu,
    const float* __restrict__ slots_logsigma, const float* __restrict__ mixing_coeffs,
    short* __restrict__ slots_bf, float* __restrict__ sigma, float* __restrict__ mixing)
{
    int b = blockIdx.x >> 3;
    int k = blockIdx.x & 7;
#pragma unroll
    for (int q = 0; q < 2; q++) {
        int d = threadIdx.x + q * 256;
        float sg = expf(slots_logsigma[k * DD + d]);
        float sl = fmaf(sg, noise_init[((size_t)(b * KK + k)) * DD + d], slots_mu[k * DD + d]);
        slots_bf[((size_t)(b * KK + k)) * DD + d] = f2bf(sl);
        sigma[((size_t)(b * KK + k)) * DD + d] = sg;
    }
    if (threadIdx.x == 0) mixing[b * KK + k] = mixing_coeffs[k];
}

// ---------------------------------------------------------------------------
// 4) bf16 MFMA GEMM: C = A(MxK=512) @ Bt^T + bias.  A row-major bf16,
//    Bt is N-major bf16 (Bt[n][k] = W[k][n]).  128x128 tile, BK=32,
//    4 waves each computing a 64x64 quadrant via 4x4 of 16x16x32 MFMAs.
//    blockIdx.z picks (Bt0,bias0,C0) vs (Bt1,bias1,C1).
// ---------------------------------------------------------------------------
__global__ __launch_bounds__(256) void gemm_mfma_kernel(
    const short* __restrict__ A,
    const short* __restrict__ Bt0, const short* __restrict__ Bt1,
    const float* __restrict__ bias0, const float* __restrict__ bias1,
    float* __restrict__ C0, float* __restrict__ C1)
{
    const short* Bt; const float* bias; float* C;
    if (blockIdx.z == 0) { Bt = Bt0; bias = bias0; C = C0; }
    else                 { Bt = Bt1; bias = bias1; C = C1; }

    __shared__ short As[128 * 32];
    __shared__ short Bs[128 * 32];

    int tid = threadIdx.x;
    int w = tid >> 6, l = tid & 63;
    int row0 = blockIdx.y * 128, col0 = blockIdx.x * 128;

    // staging: instr j covers LDS bytes [j*4096 + w*1024 + l*16]
    int srow  = w * 16 + (l >> 2);   // + j*64 -> tile row
    int selem = (l & 3) * 8;         // k-element offset within BK=32
    int lidx  = w * 512 + l * 8;     // + j*2048 (short index)

    int mq = (w & 1) * 64, nq = (w >> 1) * 64;
    int fr = l & 15, fk = (l >> 4) * 8;

    f32x4 acc[4][4] = {};

    for (int k0 = 0; k0 < DD; k0 += 32) {
        __syncthreads();
#pragma unroll
        for (int j = 0; j < 2; j++) {
            gload16(A  + (size_t)(row0 + j * 64 + srow) * DD + k0 + selem,
                    &As[j * 2048 + lidx]);
            gload16(Bt + (size_t)(col0 + j * 64 + srow) * DD + k0 + selem,
                    &Bs[j * 2048 + lidx]);
        }
        __syncthreads();

        short8 af[4], bfv[4];
#pragma unroll
        for (int mi = 0; mi < 4; mi++)
            af[mi] = *(const short8*)&As[(mq + mi * 16 + fr) * 32 + fk];
#pragma unroll
        for (int ni = 0; ni < 4; ni++)
            bfv[ni] = *(const short8*)&Bs[(nq + ni * 16 + fr) * 32 + fk];
#pragma unroll
        for (int mi = 0; mi < 4; mi++)
#pragma unroll
            for (int ni = 0; ni < 4; ni++)
                acc[mi][ni] = __builtin_amdgcn_mfma_f32_16x16x32_bf16(
                    af[mi], bfv[ni], acc[mi][ni], 0, 0, 0);
    }

    int orow = (l >> 4) * 4, ocol = l & 15;
#pragma unroll
    for (int ni = 0; ni < 4; ni++) {
        int col = col0 + nq + ni * 16 + ocol;
        float bv = bias[col];
#pragma unroll
        for (int mi = 0; mi < 4; mi++) {
#pragma unroll
            for (int r = 0; r < 4; r++) {
                int row = row0 + mq + mi * 16 + orow + r;
                C[(size_t)row * DD + col] = acc[mi][ni][r] + bv;
            }
        }
    }
}

// ---------------------------------------------------------------------------
// 5) Prep (per iteration): invvar = 1/(sigma^2+eps), logdet = sum log(|sigma|+eps)
// ---------------------------------------------------------------------------
__global__ __launch_bounds__(256) void prep_kernel(
    const float* __restrict__ sigma, float* __restrict__ invvar, float* __restrict__ logdet)
{
    int bk = blockIdx.x;
    int tid = threadIdx.x;
    float lsum = 0.0f;
    for (int d = tid; d < DD; d += 256) {
        float sg = sigma[(size_t)bk * DD + d];
        invvar[(size_t)bk * DD + d] = 1.0f / (sg * sg + EPS_);
        lsum += logf(fabsf(sg) + EPS_);
    }
    __shared__ float red[256];
    red[tid] = lsum;
    __syncthreads();
    for (int s2 = 128; s2 > 0; s2 >>= 1) {
        if (tid < s2) red[tid] += red[tid + s2];
        __syncthreads();
    }
    if (tid == 0) logdet[bk] = red[0];
}

// ---------------------------------------------------------------------------
// 6) gll + K-normalized attn + colsum.  32 rows/block, 8 rows/wave in two
//    4-row register batches (4x fewer LDS reads of qs/ivs per row).
// ---------------------------------------------------------------------------
#define GLL_ROWS 32
__global__ __launch_bounds__(256) void gll_kernel(
    const float* __restrict__ keys, const float* __restrict__ queries,
    const float* __restrict__ invvar, const float* __restrict__ logdet,
    const float* __restrict__ mixing, float* __restrict__ attn, float* __restrict__ colsum)
{
    int b  = blockIdx.y;
    int n0 = blockIdx.x * GLL_ROWS;
    int tid = threadIdx.x;

    __shared__ float qs[KK * DD];
    __shared__ float ivs[KK * DD];
    __shared__ float s_ld[KK];
    __shared__ float s_mix[KK];

    const float* qg = queries + (size_t)b * KK * DD;
    const float* ig = invvar + (size_t)b * KK * DD;
    for (int i = tid; i < KK * DD / 4; i += 256) {
        ((float4*)qs)[i]  = ((const float4*)qg)[i];
        ((float4*)ivs)[i] = ((const float4*)ig)[i];
    }
    if (tid < KK) {
        s_ld[tid]  = logdet[b * KK + tid];
        s_mix[tid] = mixing[b * KK + tid];
    }
    __syncthreads();

    int w = tid >> 6, lane = tid & 63;
    float cs_acc = 0.0f;

#pragma unroll
    for (int batch = 0; batch < 2; batch++) {
        int nb = n0 + w * 8 + batch * 4;
        float kv[4][8];
#pragma unroll
        for (int r = 0; r < 4; r++)
#pragma unroll
            for (int j = 0; j < 8; j++)
                kv[r][j] = keys[((size_t)(b * NN + nb + r)) * DD + lane + 64 * j];

        float p[4][KK] = {};
#pragma unroll
        for (int k = 0; k < KK; k++) {
#pragma unroll
            for (int j = 0; j < 8; j++) {
                int d = lane + 64 * j;
                float q  = qs[k * DD + d];
                float iv = ivs[k * DD + d];
#pragma unroll
                for (int r = 0; r < 4; r++) {
                    float df = kv[r][j] - q;
                    p[r][k] = fmaf(df * df, iv, p[r][k]);
                }
            }
        }
#pragma unroll
        for (int off = 32; off; off >>= 1)
#pragma unroll
            for (int r = 0; r < 4; r++)
#pragma unroll
                for (int k = 0; k < KK; k++) p[r][k] += __shfl_xor(p[r][k], off);

#pragma unroll
        for (int r = 0; r < 4; r++) {
            float a[KK];
            float den = 0.0f;
#pragma unroll
            for (int k = 0; k < KK; k++) {
                float g = GLL_C0 - 0.5f * s_ld[k] - 0.5f * p[r][k];
                a[k] = s_mix[k] * g;
                den += a[k];
            }
            float rden = 1.0f / den;
            if (lane < KK) {
                float v = 0.0f;
#pragma unroll
                for (int k = 0; k < KK; k++)
                    if (lane == k) v = a[k] * rden;
                attn[((size_t)(b * NN + nb + r)) * KK + lane] = v;
                cs_acc += v;
            }
        }
    }
    if (lane < KK) atomicAdd(&colsum[b * KK + lane], cs_acc);
}

// ---------------------------------------------------------------------------
// 7) musigma partials: s1/s2 over a 256-row N-chunk. grid (D/256, B, 4).
// ---------------------------------------------------------------------------
__global__ __launch_bounds__(256) void musigma_part_kernel(
    const float* __restrict__ values, const float* __restrict__ attn,
    float* __restrict__ s1p, float* __restrict__ s2p)
{
    int b = blockIdx.y, dc = blockIdx.x, ns = blockIdx.z;
    int d = dc * 256 + threadIdx.x;
    __shared__ float asml[256 * KK];
    const float* ab = attn + ((size_t)(b * NN + ns * 256)) * KK;
    for (int i = threadIdx.x; i < 256 * KK / 4; i += 256)
        ((float4*)asml)[i] = ((const float4*)ab)[i];
    __syncthreads();

    float s1[KK] = {}, s2[KK] = {};
    const float* vb = values + ((size_t)(b * NN + ns * 256)) * DD + d;
#pragma unroll 4
    for (int nn = 0; nn < 256; nn++) {
        float v = vb[(size_t)nn * DD];
        float4 a0 = *(const float4*)&asml[nn * KK];
        float4 a1 = *(const float4*)&asml[nn * KK + 4];
        float aa[8] = {a0.x, a0.y, a0.z, a0.w, a1.x, a1.y, a1.z, a1.w};
#pragma unroll
        for (int k = 0; k < KK; k++) {
            s1[k] = fmaf(aa[k], v, s1[k]);
            s2[k] = fmaf(aa[k] * v, v, s2[k]);
        }
    }
    size_t base = ((size_t)(b * 4 + ns) * KK) * DD + d;
#pragma unroll
    for (int k = 0; k < KK; k++) {
        s1p[base + (size_t)k * DD] = s1[k];
        s2p[base + (size_t)k * DD] = s2[k];
    }
}

// ---------------------------------------------------------------------------
// 8) Finalize: reduce 4 partials -> mu, sigma, mixing.
// ---------------------------------------------------------------------------
__global__ __launch_bounds__(256) void finalize_kernel(
    const float* __restrict__ s1p, const float* __restrict__ s2p,
    const float* __restrict__ colsum, float* __restrict__ mu,
    float* __restrict__ sigma, float* __restrict__ mixing)
{
    int idx = blockIdx.x * 256 + threadIdx.x;   // (b*8+k)*512+d
    int d = idx & 511;
    int k = (idx >> 9) & 7;
    int b = idx >> 12;
    float s1 = 0.0f, s2 = 0.0f;
#pragma unroll
    for (int ns = 0; ns < 4; ns++) {
        size_t off = ((size_t)(b * 4 + ns) * KK + k) * DD + d;
        s1 += s1p[off];
        s2 += s2p[off];
    }
    float cs  = colsum[b * KK + k];
    float inv = 1.0f / (cs + EPS_);
    float m   = s1 * inv;
    float sv2 = s2 * inv;
    float ssum = cs * inv;
    mu[idx] = m;
    sigma[idx] = sv2 - m * m * (2.0f - ssum);
    if (d == 0) mixing[b * KK + k] = ssum * (1.0f / NN);
}

// ---------------------------------------------------------------------------
// 9) Final outputs: slots = mu + max(|sigma|,eps)*noise_final ; attn^T
// ---------------------------------------------------------------------------
__global__ __launch_bounds__(256) void final_kernel(
    const float* __restrict__ mu, const float* __restrict__ sigma,
    const float* __restrict__ noise_final, const float* __restrict__ attn,
    const float* __restrict__ colsum, float* __restrict__ out)
{
    int gid = blockIdx.x * 256 + threadIdx.x;
    if (gid < BB * KK * DD) {
        float s = fmaxf(fabsf(sigma[gid]), EPS_);
        out[gid] = fmaf(s, noise_final[gid], mu[gid]);
    }
    if (gid < BB * KK * NN) {
        int b = gid >> 13;
        int k = (gid >> 10) & 7;
        int n = gid & 1023;
        float cs = colsum[b * KK + k];
        out[BB * KK * DD + gid] = attn[((size_t)(b * NN + n)) * KK + k] / (cs + EPS_);
    }
}

// ---------------------------------------------------------------------------
extern "C" void kernel_launch(void* const* d_in, const int* in_sizes, int n_in,
                              void* d_out, int out_size, void* d_ws, size_t ws_size,
                              hipStream_t stream)
{
    const float* emb         = (const float*)d_in[0];
    const float* noise_init  = (const float*)d_in[1];
    const float* noise_final = (const float*)d_in[2];
    const float* slots_mu    = (const float*)d_in[3];
    const float* slots_logsg = (const float*)d_in[4];
    const float* mixing_co   = (const float*)d_in[5];
    const float* Wk          = (const float*)d_in[6];
    const float* bk          = (const float*)d_in[7];
    const float* Wq          = (const float*)d_in[8];
    const float* bq          = (const float*)d_in[9];
    const float* Wv          = (const float*)d_in[10];
    const float* bv          = (const float*)d_in[11];
    const float* ln_g        = (const float*)d_in[12];
    const float* ln_b        = (const float*)d_in[13];
    float* out = (float*)d_out;

    // workspace layout
    float* ws = (float*)d_ws;
    float* keys     = ws;                               // 16*1024*512
    float* values   = keys + (size_t)BB * NN * DD;      // 16*1024*512
    float* queries  = values + (size_t)BB * NN * DD;    // 65536
    float* sigma    = queries + BB * KK * DD;           // 65536
    float* invvar   = sigma + BB * KK * DD;             // 65536
    float* mu       = invvar + BB * KK * DD;            // 65536
    float* attn     = mu + BB * KK * DD;                // 131072
    float* s1p      = attn + BB * NN * KK;              // 16*4*8*512 = 262144
    float* s2p      = s1p + BB * 4 * KK * DD;           // 262144
    float* logdet   = s2p + BB * 4 * KK * DD;           // 128
    float* mixing   = logdet + BB * KK;                 // 128
    float* colsum   = mixing + BB * KK;                 // 128
    short* Abf      = (short*)(colsum + BB * KK);       // 16*1024*512 bf16
    short* Wt       = Abf + (size_t)BB * NN * DD;       // 3*512*512 bf16
    short* slots_bf = Wt + (size_t)3 * DD * DD;         // 128*512 bf16

    ln_bf_kernel<<<BB * NN / 4, 256, 0, stream>>>(emb, ln_g, ln_b, Abf);
    wtrans_kernel<<<dim3(DD / 32, DD / 32, 3), 256, 0, stream>>>(Wk, Wv, Wq, Wt);
    init_small_kernel<<<BB * KK, 256, 0, stream>>>(
        noise_init, slots_mu, slots_logsg, mixing_co, slots_bf, sigma, mixing);

    // keys & values
    gemm_mfma_kernel<<<dim3(DD / 128, BB * NN / 128, 2), 256, 0, stream>>>(
        Abf, Wt, Wt + (size_t)DD * DD, bk, bv, keys, values);
    // queries (M = B*K = 128 rows)
    gemm_mfma_kernel<<<dim3(DD / 128, 1, 1), 256, 0, stream>>>(
        slots_bf, Wt + (size_t)2 * DD * DD, Wt + (size_t)2 * DD * DD,
        bq, bq, queries, queries);

    for (int it = 0; it < 3; it++) {
        prep_kernel<<<BB * KK, 256, 0, stream>>>(sigma, invvar, logdet);
        hipMemsetAsync(colsum, 0, BB * KK * sizeof(float), stream);
        gll_kernel<<<dim3(NN / GLL_ROWS, BB), 256, 0, stream>>>(
            keys, queries, invvar, logdet, mixing, attn, colsum);
        musigma_part_kernel<<<dim3(DD / 256, BB, 4), 256, 0, stream>>>(
            values, attn, s1p, s2p);
        finalize_kernel<<<BB * KK * DD / 256, 256, 0, stream>>>(
            s1p, s2p, colsum, mu, sigma, mixing);
    }

    final_kernel<<<(BB * KK * NN + 255) / 256, 256, 0, stream>>>(
        mu, sigma, noise_final, attn, colsum, out);
}

// Round 3
// 245.653 us; speedup vs baseline: 3.1308x; 1.2755x over previous
//
#include <hip/hip_runtime.h>
#include <math.h>

// Problem constants
#define BB 16
#define NN 1024
#define DD 512
#define KK 8
#define EPS_ 1e-8f
#define LN_EPS_ 1e-5f
// -0.5 * D * log(2*pi)
#define GLL_C0 (-470.4965290007924f)

typedef __attribute__((ext_vector_type(8))) short short8;
typedef __attribute__((ext_vector_type(4))) short short4v;
typedef __attribute__((ext_vector_type(4))) float f32x4;

// round-to-nearest-even f32 -> bf16 (as short)
static __device__ inline short f2bf(float f) {
    unsigned u = __builtin_bit_cast(unsigned, f);
    u = (u + 0x7fff + ((u >> 16) & 1)) >> 16;
    return (short)u;
}
static __device__ inline float bf2f(short s) {
    unsigned u = ((unsigned)(unsigned short)s) << 16;
    return __builtin_bit_cast(float, u);
}

static __device__ inline void gload16(const void* g, void* l) {
    __builtin_amdgcn_global_load_lds(
        (const __attribute__((address_space(1))) void*)g,
        (__attribute__((address_space(3))) void*)l, 16, 0, 0);
}

// ---------------------------------------------------------------------------
// 1) Fused LayerNorm + cast to bf16.
// ---------------------------------------------------------------------------
__global__ __launch_bounds__(256) void ln_bf_kernel(
    const float* __restrict__ emb, const float* __restrict__ lng,
    const float* __restrict__ lnb, short* __restrict__ Abf)
{
    int row  = blockIdx.x * 4 + (threadIdx.x >> 6);
    int lane = threadIdx.x & 63;
    const float* e = emb + (size_t)row * DD + lane * 8;
    float4 v0 = *(const float4*)e;
    float4 v1 = *(const float4*)(e + 4);
    float v[8] = {v0.x, v0.y, v0.z, v0.w, v1.x, v1.y, v1.z, v1.w};
    float s = 0.0f;
#pragma unroll
    for (int j = 0; j < 8; j++) s += v[j];
#pragma unroll
    for (int off = 32; off; off >>= 1) s += __shfl_xor(s, off);
    float m = s * (1.0f / DD);
    float vs = 0.0f;
#pragma unroll
    for (int j = 0; j < 8; j++) { float d = v[j] - m; vs = fmaf(d, d, vs); }
#pragma unroll
    for (int off = 32; off; off >>= 1) vs += __shfl_xor(vs, off);
    float rstd = rsqrtf(vs * (1.0f / DD) + LN_EPS_);

    float4 g0 = *(const float4*)&lng[lane * 8];
    float4 g1 = *(const float4*)&lng[lane * 8 + 4];
    float4 b0 = *(const float4*)&lnb[lane * 8];
    float4 b1 = *(const float4*)&lnb[lane * 8 + 4];
    float g[8] = {g0.x, g0.y, g0.z, g0.w, g1.x, g1.y, g1.z, g1.w};
    float bb[8] = {b0.x, b0.y, b0.z, b0.w, b1.x, b1.y, b1.z, b1.w};
    short8 o;
#pragma unroll
    for (int j = 0; j < 8; j++) o[j] = f2bf(fmaf((v[j] - m) * rstd, g[j], bb[j]));
    *(short8*)&Abf[(size_t)row * DD + lane * 8] = o;
}

// ---------------------------------------------------------------------------
// 2) Transpose + cast weights: Wt[z][n][k] = bf16(W_z[k][n]).  z: 0=Wk,1=Wv,2=Wq
// ---------------------------------------------------------------------------
__global__ __launch_bounds__(256) void wtrans_kernel(
    const float* __restrict__ Wk, const float* __restrict__ Wv,
    const float* __restrict__ Wq, short* __restrict__ Wt)
{
    const float* W = (blockIdx.z == 0) ? Wk : (blockIdx.z == 1) ? Wv : Wq;
    short* T = Wt + (size_t)blockIdx.z * DD * DD;
    int k0 = blockIdx.x * 32, n0 = blockIdx.y * 32;
    int tx = threadIdx.x & 31, ty = threadIdx.x >> 5;
    __shared__ float t[32][33];
#pragma unroll
    for (int p = 0; p < 4; p++)
        t[ty + p * 8][tx] = W[(size_t)(k0 + ty + p * 8) * DD + n0 + tx];
    __syncthreads();
#pragma unroll
    for (int p = 0; p < 4; p++)
        T[(size_t)(n0 + ty + p * 8) * DD + k0 + tx] = f2bf(t[tx][ty + p * 8]);
}

// ---------------------------------------------------------------------------
// 3) Init: slots (bf16) = mu0 + exp(logsigma)*noise_init.
// ---------------------------------------------------------------------------
__global__ __launch_bounds__(256) void init_small_kernel(
    const float* __restrict__ noise_init, const float* __restrict__ slots_mu,
    const float* __restrict__ slots_logsigma, short* __restrict__ slots_bf)
{
    int b = blockIdx.x >> 3;
    int k = blockIdx.x & 7;
#pragma unroll
    for (int q = 0; q < 2; q++) {
        int d = threadIdx.x + q * 256;
        float sg = expf(slots_logsigma[k * DD + d]);
        float sl = fmaf(sg, noise_init[((size_t)(b * KK + k)) * DD + d], slots_mu[k * DD + d]);
        slots_bf[((size_t)(b * KK + k)) * DD + d] = f2bf(sl);
    }
}

// ---------------------------------------------------------------------------
// 4) bf16 MFMA GEMM, 128x128 tile, BK=32.  Epilogue modes:
//    qmode==0: z=0 -> E[row][col]=bf16((c)^2), E[row][512+col]=bf16(c)  (keys)
//              z=1 -> Vbf[row][col]=bf16(c)                             (values)
//    qmode==1: Cq[row][col]=c (fp32, queries)
// ---------------------------------------------------------------------------
__global__ __launch_bounds__(256) void gemm_mfma_kernel(
    const short* __restrict__ A,
    const short* __restrict__ Bt0, const short* __restrict__ Bt1,
    const float* __restrict__ bias0, const float* __restrict__ bias1,
    short* __restrict__ E, short* __restrict__ Vbf, float* __restrict__ Cq,
    int qmode)
{
    const short* Bt; const float* bias;
    int z = blockIdx.z;
    if (z == 0) { Bt = Bt0; bias = bias0; }
    else        { Bt = Bt1; bias = bias1; }

    __shared__ short As[128 * 32];
    __shared__ short Bs[128 * 32];

    int tid = threadIdx.x;
    int w = tid >> 6, l = tid & 63;
    int row0 = blockIdx.y * 128, col0 = blockIdx.x * 128;

    int srow  = w * 16 + (l >> 2);
    int selem = (l & 3) * 8;
    int lidx  = w * 512 + l * 8;

    int mq = (w & 1) * 64, nq = (w >> 1) * 64;
    int fr = l & 15, fk = (l >> 4) * 8;

    f32x4 acc[4][4] = {};

    for (int k0 = 0; k0 < DD; k0 += 32) {
        __syncthreads();
#pragma unroll
        for (int j = 0; j < 2; j++) {
            gload16(A  + (size_t)(row0 + j * 64 + srow) * DD + k0 + selem,
                    &As[j * 2048 + lidx]);
            gload16(Bt + (size_t)(col0 + j * 64 + srow) * DD + k0 + selem,
                    &Bs[j * 2048 + lidx]);
        }
        __syncthreads();

        short8 af[4], bfv[4];
#pragma unroll
        for (int mi = 0; mi < 4; mi++)
            af[mi] = *(const short8*)&As[(mq + mi * 16 + fr) * 32 + fk];
#pragma unroll
        for (int ni = 0; ni < 4; ni++)
            bfv[ni] = *(const short8*)&Bs[(nq + ni * 16 + fr) * 32 + fk];
#pragma unroll
        for (int mi = 0; mi < 4; mi++)
#pragma unroll
            for (int ni = 0; ni < 4; ni++)
                acc[mi][ni] = __builtin_amdgcn_mfma_f32_16x16x32_bf16(
                    af[mi], bfv[ni], acc[mi][ni], 0, 0, 0);
    }

    int orow = (l >> 4) * 4, ocol = l & 15;
#pragma unroll
    for (int ni = 0; ni < 4; ni++) {
        int col = col0 + nq + ni * 16 + ocol;
        float bv = bias[col];
#pragma unroll
        for (int mi = 0; mi < 4; mi++) {
#pragma unroll
            for (int r = 0; r < 4; r++) {
                int row = row0 + mq + mi * 16 + orow + r;
                float val = acc[mi][ni][r] + bv;
                if (qmode) {
                    Cq[(size_t)row * DD + col] = val;
                } else if (z == 0) {
                    E[(size_t)row * 1024 + col]       = f2bf(val * val);
                    E[(size_t)row * 1024 + 512 + col] = f2bf(val);
                } else {
                    Vbf[(size_t)row * DD + col] = f2bf(val);
                }
            }
        }
    }
}

// ---------------------------------------------------------------------------
// 5) fprep0: initial F/off/mix from exp(logsigma) + queries; zero k>=8 rows.
//    grid (BB, 16), 256 threads, 2 d per thread.
// ---------------------------------------------------------------------------
__global__ __launch_bounds__(256) void fprep0_kernel(
    const float* __restrict__ slots_logsigma, const float* __restrict__ queries,
    const float* __restrict__ mixing_coeffs, short* __restrict__ F_bt,
    float* __restrict__ off, float* __restrict__ mix16, float* __restrict__ colsum)
{
    int b = blockIdx.x, k = blockIdx.y;
    int tid = threadIdx.x;
    short* Fr = F_bt + (size_t)(b * 16 + k) * 1024;
    if (k >= KK) {
        short4v z = {0, 0, 0, 0};
        *(short4v*)&Fr[tid * 4] = z;
        if (tid == 0) { off[b * 16 + k] = 0.0f; mix16[b * 16 + k] = 0.0f; }
        return;
    }
    float c = 0.0f, ld = 0.0f;
#pragma unroll
    for (int q = 0; q < 2; q++) {
        int d = tid * 2 + q;
        float sg = expf(slots_logsigma[k * DD + d]);
        float iv = 1.0f / (sg * sg + EPS_);
        float qv = queries[((size_t)(b * KK + k)) * DD + d];
        Fr[d]       = f2bf(-0.5f * iv);
        Fr[512 + d] = f2bf(qv * iv);
        c  = fmaf(qv * qv, iv, c);
        ld += logf(fabsf(sg) + EPS_);
    }
    __shared__ float rc[256], rl[256];
    rc[tid] = c; rl[tid] = ld;
    __syncthreads();
    for (int s = 128; s > 0; s >>= 1) {
        if (tid < s) { rc[tid] += rc[tid + s]; rl[tid] += rl[tid + s]; }
        __syncthreads();
    }
    if (tid == 0) {
        off[b * 16 + k]   = GLL_C0 - 0.5f * rl[0] - 0.5f * rc[0];
        mix16[b * 16 + k] = mixing_coeffs[k];
        colsum[b * KK + k] = 0.0f;
    }
}

// ---------------------------------------------------------------------------
// 6) gll as batched MFMA GEMM: gll[n][k'] = E[n][:] . F_bt[k'][:] + off[k'].
//    Epilogue: a = mix*g; den = sum over 16 cols (shuffle); attn = a/den;
//    colsum accumulated via atomics.  grid (16 mtiles, BB), 4 waves x 16 rows.
// ---------------------------------------------------------------------------
__global__ __launch_bounds__(256) void gll_mfma_kernel(
    const short* __restrict__ E, const short* __restrict__ F_bt,
    const float* __restrict__ off, const float* __restrict__ mix16,
    float* __restrict__ attn, float* __restrict__ colsum)
{
    int b = blockIdx.y;
    int tid = threadIdx.x;
    int w = tid >> 6, l = tid & 63;
    int m0 = blockIdx.x * 64 + w * 16;       // row within this b

    const short* Ea = E + ((size_t)(b * NN + m0 + (l & 15))) * 1024 + (l >> 4) * 8;
    const short* Fa = F_bt + (size_t)(b * 16 + (l & 15)) * 1024 + (l >> 4) * 8;

    f32x4 acc = {};
#pragma unroll 8
    for (int k0 = 0; k0 < 1024; k0 += 32) {
        short8 af = *(const short8*)&Ea[k0];
        short8 bf = *(const short8*)&Fa[k0];
        acc = __builtin_amdgcn_mfma_f32_16x16x32_bf16(af, bf, acc, 0, 0, 0);
    }

    int col = l & 15;
    int rbase = m0 + (l >> 4) * 4;
    float offv = off[b * 16 + col];
    float mixv = mix16[b * 16 + col];

    float a[4], den[4];
#pragma unroll
    for (int r = 0; r < 4; r++) {
        a[r] = mixv * (acc[r] + offv);
        den[r] = a[r];
    }
#pragma unroll
    for (int mask = 1; mask <= 8; mask <<= 1)
#pragma unroll
        for (int r = 0; r < 4; r++) den[r] += __shfl_xor(den[r], mask);

    float csl = 0.0f;
    if (col < KK) {
#pragma unroll
        for (int r = 0; r < 4; r++) {
            float v = a[r] / den[r];
            attn[((size_t)(b * NN + rbase + r)) * KK + col] = v;
            csl += v;
        }
    }
    csl += __shfl_xor(csl, 16);
    csl += __shfl_xor(csl, 32);
    if (l < KK) atomicAdd(&colsum[b * KK + l], csl);
}

// ---------------------------------------------------------------------------
// 7) musigma partials over 64-row chunks: s1 = sum a*v, s2 = sum a*v^2.
//    grid (BB, 16).  bf16 values, 2 d per thread.
// ---------------------------------------------------------------------------
__global__ __launch_bounds__(256) void musigma_kernel(
    const short* __restrict__ Vbf, const float* __restrict__ attn,
    float* __restrict__ s1p, float* __restrict__ s2p)
{
    int b = blockIdx.x, ns = blockIdx.y;
    int tid = threadIdx.x;
    int d0 = tid * 2;
    __shared__ float asml[64 * KK];
    const float* ab = attn + ((size_t)(b * NN + ns * 64)) * KK;
    if (tid < 128) ((float4*)asml)[tid] = ((const float4*)ab)[tid];
    __syncthreads();

    float s1[2][KK] = {}, s2[2][KK] = {};
    const short* vb = Vbf + ((size_t)(b * NN + ns * 64)) * DD + d0;
#pragma unroll 4
    for (int nn = 0; nn < 64; nn++) {
        short2 vs = *(const short2*)&vb[(size_t)nn * DD];
        float v0 = bf2f(vs.x), v1 = bf2f(vs.y);
        float v0q = v0 * v0, v1q = v1 * v1;
#pragma unroll
        for (int k = 0; k < KK; k++) {
            float a = asml[nn * KK + k];
            s1[0][k] = fmaf(a, v0, s1[0][k]);
            s2[0][k] = fmaf(a, v0q, s2[0][k]);
            s1[1][k] = fmaf(a, v1, s1[1][k]);
            s2[1][k] = fmaf(a, v1q, s2[1][k]);
        }
    }
    size_t base = ((size_t)(b * 16 + ns) * KK) * DD + d0;
#pragma unroll
    for (int k = 0; k < KK; k++) {
        *(float2*)&s1p[base + (size_t)k * DD] = make_float2(s1[0][k], s1[1][k]);
        *(float2*)&s2p[base + (size_t)k * DD] = make_float2(s2[0][k], s2[1][k]);
    }
}

// ---------------------------------------------------------------------------
// 8) fprep_fused: finalize (mu/sigma from partials) + next-iter F/off/mix +
//    colsum reset.  grid (BB, 8).
// ---------------------------------------------------------------------------
__global__ __launch_bounds__(256) void fprep_fused_kernel(
    const float* __restrict__ s1p, const float* __restrict__ s2p,
    const float* __restrict__ queries, float* __restrict__ colsum,
    short* __restrict__ F_bt, float* __restrict__ off, float* __restrict__ mix16)
{
    int b = blockIdx.x, k = blockIdx.y;
    int tid = threadIdx.x;
    float cs   = colsum[b * KK + k];
    float inv  = 1.0f / (cs + EPS_);
    float ssum = cs * inv;
    short* Fr = F_bt + (size_t)(b * 16 + k) * 1024;

    float c = 0.0f, ld = 0.0f;
#pragma unroll
    for (int q = 0; q < 2; q++) {
        int d = tid * 2 + q;
        float s1 = 0.0f, s2 = 0.0f;
#pragma unroll
        for (int ns = 0; ns < 16; ns++) {
            size_t o = ((size_t)(b * 16 + ns) * KK + k) * DD + d;
            s1 += s1p[o];
            s2 += s2p[o];
        }
        float m  = s1 * inv;
        float sg = s2 * inv - m * m * (2.0f - ssum);
        float iv = 1.0f / (sg * sg + EPS_);
        float qv = queries[((size_t)(b * KK + k)) * DD + d];
        Fr[d]       = f2bf(-0.5f * iv);
        Fr[512 + d] = f2bf(qv * iv);
        c  = fmaf(qv * qv, iv, c);
        ld += logf(fabsf(sg) + EPS_);
    }
    __shared__ float rc[256], rl[256];
    rc[tid] = c; rl[tid] = ld;
    __syncthreads();
    for (int s = 128; s > 0; s >>= 1) {
        if (tid < s) { rc[tid] += rc[tid + s]; rl[tid] += rl[tid + s]; }
        __syncthreads();
    }
    if (tid == 0) {
        off[b * 16 + k]    = GLL_C0 - 0.5f * rl[0] - 0.5f * rc[0];
        mix16[b * 16 + k]  = ssum * (1.0f / NN);
        colsum[b * KK + k] = 0.0f;
    }
}

// ---------------------------------------------------------------------------
// 9) Final: finalize last iter (mu/sigma from partials) -> slots out; attn^T.
// ---------------------------------------------------------------------------
__global__ __launch_bounds__(256) void final_kernel(
    const float* __restrict__ s1p, const float* __restrict__ s2p,
    const float* __restrict__ colsum, const float* __restrict__ noise_final,
    const float* __restrict__ attn, float* __restrict__ out)
{
    int gid = blockIdx.x * 256 + threadIdx.x;
    if (gid < BB * KK * DD) {
        int d = gid & 511;
        int k = (gid >> 9) & 7;
        int b = gid >> 12;
        float s1 = 0.0f, s2 = 0.0f;
#pragma unroll
        for (int ns = 0; ns < 16; ns++) {
            size_t o = ((size_t)(b * 16 + ns) * KK + k) * DD + d;
            s1 += s1p[o];
            s2 += s2p[o];
        }
        float cs   = colsum[b * KK + k];
        float inv  = 1.0f / (cs + EPS_);
        float ssum = cs * inv;
        float m    = s1 * inv;
        float sg   = s2 * inv - m * m * (2.0f - ssum);
        out[gid] = fmaf(fmaxf(fabsf(sg), EPS_), noise_final[gid], m);
    }
    if (gid < BB * KK * NN) {
        int b = gid >> 13;
        int k = (gid >> 10) & 7;
        int n = gid & 1023;
        float cs = colsum[b * KK + k];
        out[BB * KK * DD + gid] = attn[((size_t)(b * NN + n)) * KK + k] / (cs + EPS_);
    }
}

// ---------------------------------------------------------------------------
extern "C" void kernel_launch(void* const* d_in, const int* in_sizes, int n_in,
                              void* d_out, int out_size, void* d_ws, size_t ws_size,
                              hipStream_t stream)
{
    const float* emb         = (const float*)d_in[0];
    const float* noise_init  = (const float*)d_in[1];
    const float* noise_final = (const float*)d_in[2];
    const float* slots_mu    = (const float*)d_in[3];
    const float* slots_logsg = (const float*)d_in[4];
    const float* mixing_co   = (const float*)d_in[5];
    const float* Wk          = (const float*)d_in[6];
    const float* bk          = (const float*)d_in[7];
    const float* Wq          = (const float*)d_in[8];
    const float* bq          = (const float*)d_in[9];
    const float* Wv          = (const float*)d_in[10];
    const float* bv          = (const float*)d_in[11];
    const float* ln_g        = (const float*)d_in[12];
    const float* ln_b        = (const float*)d_in[13];
    float* out = (float*)d_out;

    // workspace layout
    float* ws = (float*)d_ws;
    float* queries = ws;                                 // 65536
    float* attn    = queries + BB * KK * DD;             // 131072
    float* s1p     = attn + BB * NN * KK;                // 16*16*8*512 = 1048576
    float* s2p     = s1p + (size_t)BB * 16 * KK * DD;    // 1048576
    float* off     = s2p + (size_t)BB * 16 * KK * DD;    // 256
    float* mix16   = off + BB * 16;                      // 256
    float* colsum  = mix16 + BB * 16;                    // 128
    short* Abf     = (short*)(colsum + BB * KK);         // 16*1024*512
    short* E       = Abf + (size_t)BB * NN * DD;         // 16*1024*1024
    short* Vbf     = E + (size_t)BB * NN * 1024;         // 16*1024*512
    short* Wt      = Vbf + (size_t)BB * NN * DD;         // 3*512*512
    short* slotbf  = Wt + (size_t)3 * DD * DD;           // 128*512
    short* F_bt    = slotbf + (size_t)BB * KK * DD;      // 16*16*1024

    ln_bf_kernel<<<BB * NN / 4, 256, 0, stream>>>(emb, ln_g, ln_b, Abf);
    wtrans_kernel<<<dim3(DD / 32, DD / 32, 3), 256, 0, stream>>>(Wk, Wv, Wq, Wt);
    init_small_kernel<<<BB * KK, 256, 0, stream>>>(
        noise_init, slots_mu, slots_logsg, slotbf);

    // keys -> E (k^2 | k), values -> Vbf
    gemm_mfma_kernel<<<dim3(DD / 128, BB * NN / 128, 2), 256, 0, stream>>>(
        Abf, Wt, Wt + (size_t)DD * DD, bk, bv, E, Vbf, nullptr, 0);
    // queries fp32 (M = 128 rows)
    gemm_mfma_kernel<<<dim3(DD / 128, 1, 1), 256, 0, stream>>>(
        slotbf, Wt + (size_t)2 * DD * DD, Wt + (size_t)2 * DD * DD,
        bq, bq, nullptr, nullptr, queries, 1);

    fprep0_kernel<<<dim3(BB, 16), 256, 0, stream>>>(
        slots_logsg, queries, mixing_co, F_bt, off, mix16, colsum);

    for (int it = 0; it < 3; it++) {
        gll_mfma_kernel<<<dim3(16, BB), 256, 0, stream>>>(
            E, F_bt, off, mix16, attn, colsum);
        musigma_kernel<<<dim3(BB, 16), 256, 0, stream>>>(Vbf, attn, s1p, s2p);
        if (it < 2)
            fprep_fused_kernel<<<dim3(BB, KK), 256, 0, stream>>>(
                s1p, s2p, queries, colsum, F_bt, off, mix16);
    }

    final_kernel<<<BB * KK * NN / 256, 256, 0, stream>>>(
        s1p, s2p, colsum, noise_final, attn, out);
}